// Round 1
// baseline (115.705 us; speedup 1.0000x reference)
//
#include <hip/hip_runtime.h>

// Periodic (wrap) padding of [B=8, C=4, 128,128,128] f32 by PAD=2 on the 3
// spatial dims -> [8, 4, 132,132,132].
// Pure memory-bound copy: coalesced float4 writes, gather reads with wrap.

#define PADW 2
#define NIN 128
#define NOUT 132                 // NIN + 2*PADW
#define QPR (NOUT / 4)           // 33 float4 quads per output row (exact)

__global__ __launch_bounds__(256) void periodic_pad3d_kernel(
    const float* __restrict__ in, float* __restrict__ out, unsigned n_quads) {
    unsigned idx = blockIdx.x * blockDim.x + threadIdx.x;
    unsigned stride = gridDim.x * blockDim.x;

    for (unsigned q = idx; q < n_quads; q += stride) {
        // Decode output coords. All 32-bit: out elements = 73,598,976 < 2^31.
        unsigned qw  = q % QPR;          // quad index within row [0,33)
        unsigned row = q / QPR;          // global row id
        unsigned h_out = row % NOUT;
        unsigned rem   = row / NOUT;
        unsigned d_out = rem % NOUT;
        unsigned bc    = rem / NOUT;     // b*C + c in [0,32)

        // Wrap d/h once (branchless): src = (out - PAD) mod 128
        int d_src = (int)d_out - PADW;
        d_src += (d_src < 0) ? NIN : 0;
        d_src -= (d_src >= NIN) ? NIN : 0;
        int h_src = (int)h_out - PADW;
        h_src += (h_src < 0) ? NIN : 0;
        h_src -= (h_src >= NIN) ? NIN : 0;

        const float* __restrict__ src_row =
            in + (((bc * NIN + (unsigned)d_src) * NIN + (unsigned)h_src) << 7); // *NIN

        float4 v;
        int w0 = (int)(qw << 2) - PADW;  // first source w (may be <0 or >=128)
        {
            int w = w0;     w += (w < 0) ? NIN : 0; w -= (w >= NIN) ? NIN : 0; v.x = src_row[w];
        }
        {
            int w = w0 + 1; w += (w < 0) ? NIN : 0; w -= (w >= NIN) ? NIN : 0; v.y = src_row[w];
        }
        {
            int w = w0 + 2; w += (w < 0) ? NIN : 0; w -= (w >= NIN) ? NIN : 0; v.z = src_row[w];
        }
        {
            int w = w0 + 3; w += (w < 0) ? NIN : 0; w -= (w >= NIN) ? NIN : 0; v.w = src_row[w];
        }

        // Output rows are 528 B apart (16B-aligned) and quads tile rows exactly,
        // so every quad write is 16B-aligned.
        *reinterpret_cast<float4*>(out + ((size_t)q << 2)) = v;
    }
}

extern "C" void kernel_launch(void* const* d_in, const int* in_sizes, int n_in,
                              void* d_out, int out_size, void* d_ws, size_t ws_size,
                              hipStream_t stream) {
    const float* x = (const float*)d_in[0];
    float* out = (float*)d_out;

    // out_size = 8*4*132^3 = 73,598,976 ; divisible by 4.
    unsigned n_quads = (unsigned)out_size / 4;

    const int block = 256;
    unsigned blocks_needed = (n_quads + block - 1) / block;
    unsigned grid = blocks_needed < 2048u ? blocks_needed : 2048u;

    periodic_pad3d_kernel<<<grid, block, 0, stream>>>(x, out, n_quads);
}

// Round 2
// 86.574 us; speedup vs baseline: 1.3365x; 1.3365x over previous
//
#include <hip/hip_runtime.h>

// Periodic (wrap) padding of [B=8, C=4, 128,128,128] f32 by PAD=2 on the 3
// spatial dims -> [8, 4, 132,132,132].
//
// One output float4 quad per thread, exact grid (no loop).
// Key trick: w0 = 4*qw - 2 is even, so every quad (including the two wrap
// quads at row edges) is exactly two 8B-aligned float2 loads:
//   qw=0  -> {src[126..127], src[0..1]}
//   qw=32 -> {src[126..127], src[0..1]}
//   else  -> {src[w0..w0+1], src[w0+2..w0+3]}
// Branchless, no divergence. Stores are nontemporal (write-once stream).

#define PADW 2
#define NIN 128
#define NOUT 132
#define QPR 33                   // float4 quads per output row (132/4)

typedef float f4 __attribute__((ext_vector_type(4)));

__global__ __launch_bounds__(256) void periodic_pad3d_kernel(
    const float* __restrict__ in, float* __restrict__ out) {
    unsigned q = blockIdx.x * 256u + threadIdx.x;   // exact: grid*256 == n_quads

    // Decode output coords (32-bit magic-mul div/mod).
    unsigned qw  = q % QPR;
    unsigned row = q / QPR;
    unsigned h_out = row % NOUT;
    unsigned rem   = row / NOUT;
    unsigned d_out = rem % NOUT;
    unsigned bc    = rem / NOUT;     // b*C + c in [0,32)

    // Wrap d/h once (branchless): src = (out - PAD) mod 128
    int d_src = (int)d_out - PADW;
    d_src += (d_src < 0) ? NIN : 0;
    d_src -= (d_src >= NIN) ? NIN : 0;
    int h_src = (int)h_out - PADW;
    h_src += (h_src < 0) ? NIN : 0;
    h_src -= (h_src >= NIN) ? NIN : 0;

    const float* __restrict__ src_row =
        in + (((bc * NIN + (unsigned)d_src) * NIN + (unsigned)h_src) << 7);

    int w0 = (int)(qw << 2) - PADW;          // even, in [-2, 126]
    int a = w0 + ((w0 < 0) ? NIN : 0);       // qw==0 -> 126, else w0
    int b = w0 + 2;
    b -= (b >= NIN) ? NIN : 0;               // qw==32 -> 0, else w0+2

    float2 lo = *reinterpret_cast<const float2*>(src_row + a);
    float2 hi = *reinterpret_cast<const float2*>(src_row + b);

    f4 v = {lo.x, lo.y, hi.x, hi.y};
    // Output rows are 528 B apart and quads tile rows exactly -> 16B-aligned.
    __builtin_nontemporal_store(v, reinterpret_cast<f4*>(out) + q);
}

extern "C" void kernel_launch(void* const* d_in, const int* in_sizes, int n_in,
                              void* d_out, int out_size, void* d_ws, size_t ws_size,
                              hipStream_t stream) {
    const float* x = (const float*)d_in[0];
    float* out = (float*)d_out;

    // out_size = 8*4*132^3 = 73,598,976 ; /4 = 18,399,744 quads = 71,874 * 256.
    unsigned n_quads = (unsigned)out_size / 4;
    unsigned grid = n_quads / 256u;          // exact division for this shape

    periodic_pad3d_kernel<<<grid, 256, 0, stream>>>(x, out);
}